// Round 1
// baseline (84.539 us; speedup 1.0000x reference)
//
#include <hip/hip_runtime.h>

typedef float  f32x4 __attribute__((ext_vector_type(4)));
typedef _Float16 half8 __attribute__((ext_vector_type(8)));

constexpr int NB = 8;
constexpr int NQ = 2048;
constexpr int NKEY = 2048;
constexpr int DD = 64;
constexpr int KB = 32;   // keys per KV tile

__global__ __launch_bounds__(256) void attn_fwd(
    const float* __restrict__ Qp, const float* __restrict__ Kp,
    const float* __restrict__ Vp, const int* __restrict__ VL,
    float* __restrict__ Op)
{
    // K tile: 32 keys x 64 d halves, rows of 128B, XOR-swizzled
    __shared__ alignas(16) char Ksm[KB * DD * 2];
    // V tile transposed: 64 d x 32 keys halves (64B rows)
    __shared__ alignas(16) char Vsm[DD * KB * 2];
    // per-wave P buffer: 16 q x 32 keys halves, swizzled
    __shared__ alignas(16) char Psm[4 * 16 * KB * 2];

    const int tid  = threadIdx.x;
    const int wv   = tid >> 6;
    const int lane = tid & 63;
    const int g    = lane >> 4;   // 0..3
    const int lr   = lane & 15;   // 0..15

    const int bidx = blockIdx.x;
    const int b  = bidx >> 5;     // 32 q-tiles per batch
    const int qt = bidx & 31;

    const int vlen = VL[b];
    const int numt = (vlen + KB - 1) / KB;

    // ---- load Q fragments (A-operand), fold in 1/sqrt(64) = 0.125 ----
    // A layout: row = lr, k = g*8 + j  (within each 32-wide d chunk)
    const int qrowA = qt * 64 + wv * 16 + lr;
    const float* qsrc = Qp + ((size_t)b * NQ + qrowA) * DD;
    half8 qf[2];
#pragma unroll
    for (int c = 0; c < 2; ++c) {
        f32x4 f0 = *(const f32x4*)(qsrc + c * 32 + g * 8);
        f32x4 f1 = *(const f32x4*)(qsrc + c * 32 + g * 8 + 4);
        half8 h;
#pragma unroll
        for (int j = 0; j < 4; ++j) {
            h[j]     = (_Float16)(f0[j] * 0.125f);
            h[4 + j] = (_Float16)(f1[j] * 0.125f);
        }
        qf[c] = h;
    }

    // ---- accumulators ----
    f32x4 o[4];
    const f32x4 zf = {0.f, 0.f, 0.f, 0.f};
#pragma unroll
    for (int t = 0; t < 4; ++t) o[t] = zf;
    float mrun[4], lrun[4];
#pragma unroll
    for (int r = 0; r < 4; ++r) { mrun[r] = -1e30f; lrun[r] = 0.f; }

    // staging assignments
    const int skey = tid >> 3;          // 0..31
    const int sd0  = (tid & 7) * 8;     // 0..56
    const int vkey = tid & 31;          // 0..31
    const int vd0  = (tid >> 5) * 8;    // 0..56

    for (int it = 0; it < numt; ++it) {
        const int kbase = it * KB;
        __syncthreads();   // previous tile consumed

        // ---- stage K tile (f32 -> f16), swizzled rows ----
        {
            const float* src = Kp + ((size_t)b * NKEY + kbase + skey) * DD + sd0;
            f32x4 f0 = *(const f32x4*)src;
            f32x4 f1 = *(const f32x4*)(src + 4);
            half8 h;
#pragma unroll
            for (int j = 0; j < 4; ++j) {
                h[j]     = (_Float16)f0[j];
                h[4 + j] = (_Float16)f1[j];
            }
            const int off = (skey * 128 + sd0 * 2) ^ ((skey & 7) << 4);
            *(half8*)(Ksm + off) = h;
        }
        // ---- stage V tile transposed ----
        {
            const float* src = Vp + ((size_t)b * NKEY + kbase + vkey) * DD + vd0;
            f32x4 f0 = *(const f32x4*)src;
            f32x4 f1 = *(const f32x4*)(src + 4);
#pragma unroll
            for (int j = 0; j < 8; ++j) {
                const float x = (j < 4) ? f0[j] : f1[j - 4];
                *(_Float16*)(Vsm + (vd0 + j) * (KB * 2) + vkey * 2) = (_Float16)x;
            }
        }
        __syncthreads();   // tile staged

        // ---- QK^T: S tile 16q x 32keys, two 16-col sub-tiles ----
        f32x4 s0 = zf, s1 = zf;
#pragma unroll
        for (int c = 0; c < 2; ++c) {
            const int key0 = lr;
            const half8 kb0 = *(const half8*)(Ksm +
                ((key0 * 128 + c * 64 + g * 16) ^ ((key0 & 7) << 4)));
            s0 = __builtin_amdgcn_mfma_f32_16x16x32_f16(qf[c], kb0, s0, 0, 0, 0);
            const int key1 = 16 + lr;
            const half8 kb1 = *(const half8*)(Ksm +
                ((key1 * 128 + c * 64 + g * 16) ^ ((key1 & 7) << 4)));
            s1 = __builtin_amdgcn_mfma_f32_16x16x32_f16(qf[c], kb1, s1, 0, 0, 0);
        }

        // ---- masked online softmax (rows = g*4+r, cols = lr) ----
        const bool msk0 = (kbase + lr) >= vlen;
        const bool msk1 = (kbase + 16 + lr) >= vlen;
        float alpha[4];
        f32x4 p0, p1;
#pragma unroll
        for (int r = 0; r < 4; ++r) {
            const float v0 = msk0 ? -1e30f : s0[r];
            const float v1 = msk1 ? -1e30f : s1[r];
            float mr = fmaxf(v0, v1);
            mr = fmaxf(mr, __shfl_xor(mr, 1));
            mr = fmaxf(mr, __shfl_xor(mr, 2));
            mr = fmaxf(mr, __shfl_xor(mr, 4));
            mr = fmaxf(mr, __shfl_xor(mr, 8));
            const float mn = fmaxf(mrun[r], mr);
            alpha[r] = __expf(mrun[r] - mn);
            mrun[r] = mn;
            const float e0 = __expf(v0 - mn);
            const float e1 = __expf(v1 - mn);
            p0[r] = e0; p1[r] = e1;
            float ps = e0 + e1;
            ps += __shfl_xor(ps, 1);
            ps += __shfl_xor(ps, 2);
            ps += __shfl_xor(ps, 4);
            ps += __shfl_xor(ps, 8);
            lrun[r] = lrun[r] * alpha[r] + ps;
        }

        // ---- write P (C-layout) to per-wave LDS, swizzled ----
        char* pw = Psm + wv * (16 * KB * 2);
#pragma unroll
        for (int r = 0; r < 4; ++r) {
            const int q = g * 4 + r;
            const int xm = (g & 3) << 4;   // ((q>>2)&3)<<4
            *(_Float16*)(pw + q * 64 + ((lr * 2) ^ xm))        = (_Float16)p0[r];
            *(_Float16*)(pw + q * 64 + (((16 + lr) * 2) ^ xm)) = (_Float16)p1[r];
        }

        // ---- rescale O by alpha ----
#pragma unroll
        for (int t = 0; t < 4; ++t) {
#pragma unroll
            for (int r = 0; r < 4; ++r) o[t][r] *= alpha[r];
        }

        // ---- read P as A-frag, PV MFMAs ----
        const half8 pa = *(const half8*)(pw + lr * 64 +
                           ((g * 16) ^ (((lr >> 2) & 3) << 4)));
#pragma unroll
        for (int t = 0; t < 4; ++t) {
            const half8 vb = *(const half8*)(Vsm + (t * 16 + lr) * 64 + g * 16);
            o[t] = __builtin_amdgcn_mfma_f32_16x16x32_f16(pa, vb, o[t], 0, 0, 0);
        }
    }

    // ---- epilogue: normalize and store (D rows = g*4+r, cols = lr+16t) ----
#pragma unroll
    for (int r = 0; r < 4; ++r) {
        const float inv = 1.0f / lrun[r];
        const int qrow = qt * 64 + wv * 16 + g * 4 + r;
        float* dst = Op + ((size_t)b * NQ + qrow) * DD;
#pragma unroll
        for (int t = 0; t < 4; ++t)
            dst[t * 16 + lr] = o[t][r] * inv;
    }
}

extern "C" void kernel_launch(void* const* d_in, const int* in_sizes, int n_in,
                              void* d_out, int out_size, void* d_ws, size_t ws_size,
                              hipStream_t stream) {
    const float* Qp = (const float*)d_in[0];
    const float* Kp = (const float*)d_in[1];
    const float* Vp = (const float*)d_in[2];
    const int*   VL = (const int*)d_in[3];
    float* Op = (float*)d_out;

    dim3 grid(NB * (NQ / 64));   // 256 blocks
    dim3 block(256);
    hipLaunchKernelGGL(attn_fwd, grid, block, 0, stream, Qp, Kp, Vp, VL, Op);
}

// Round 2
// 48.274 us; speedup vs baseline: 1.7512x; 1.7512x over previous
//
#include <hip/hip_runtime.h>

typedef float  f32x4 __attribute__((ext_vector_type(4)));
typedef _Float16 half8 __attribute__((ext_vector_type(8)));

constexpr int NB = 8;
constexpr int NQ = 2048;
constexpr int NKEY = 2048;
constexpr int DD = 64;
constexpr int KB = 32;   // keys per KV tile

// ---------------- kernel 1: per-segment flash partials ----------------
__global__ __launch_bounds__(256) void attn_partial(
    const float* __restrict__ Qp, const float* __restrict__ Kp,
    const float* __restrict__ Vp, const int* __restrict__ VL,
    float* __restrict__ Opart, float2* __restrict__ ml,
    float* __restrict__ Op, int nseg)
{
    __shared__ alignas(16) char Ksm[KB * DD * 2];
    __shared__ alignas(16) char Vsm[DD * KB * 2];
    __shared__ alignas(16) char Psm[4 * 16 * KB * 2];

    const int tid  = threadIdx.x;
    const int wv   = tid >> 6;
    const int lane = tid & 63;
    const int g    = lane >> 4;   // 0..3
    const int lr   = lane & 15;   // 0..15

    const int s   = blockIdx.x / (NB * 32);
    const int rem = blockIdx.x % (NB * 32);
    const int b   = rem >> 5;
    const int qt  = rem & 31;

    const int vlen = VL[b];
    const int SEG  = NKEY / nseg;
    const int kstart = s * SEG;
    const int kend   = min(kstart + SEG, vlen);

    if (kstart >= vlen) {
        // empty segment: mark l=0 so merge skips it
        if (tid < 64) {
            const int qrow = qt * 64 + tid;
            ml[(size_t)(b * nseg + s) * NQ + qrow] = make_float2(-1e30f, 0.f);
        }
        return;
    }

    // ---- load Q fragments (A-operand), fold in 1/sqrt(64) = 0.125 ----
    const int qrowA = qt * 64 + wv * 16 + lr;
    const float* qsrc = Qp + ((size_t)b * NQ + qrowA) * DD;
    half8 qf[2];
#pragma unroll
    for (int c = 0; c < 2; ++c) {
        f32x4 f0 = *(const f32x4*)(qsrc + c * 32 + g * 8);
        f32x4 f1 = *(const f32x4*)(qsrc + c * 32 + g * 8 + 4);
        half8 h;
#pragma unroll
        for (int j = 0; j < 4; ++j) {
            h[j]     = (_Float16)(f0[j] * 0.125f);
            h[4 + j] = (_Float16)(f1[j] * 0.125f);
        }
        qf[c] = h;
    }

    f32x4 o[4];
    const f32x4 zf = {0.f, 0.f, 0.f, 0.f};
#pragma unroll
    for (int t = 0; t < 4; ++t) o[t] = zf;
    float mrun[4], lrun[4];
#pragma unroll
    for (int r = 0; r < 4; ++r) { mrun[r] = -1e30f; lrun[r] = 0.f; }

    const int skey = tid >> 3;
    const int sd0  = (tid & 7) * 8;
    const int vkey = tid & 31;
    const int vd0  = (tid >> 5) * 8;

    const int numt = (kend - kstart + KB - 1) / KB;

    for (int it = 0; it < numt; ++it) {
        const int kbase = kstart + it * KB;
        __syncthreads();

        // ---- stage K tile (f32 -> f16), swizzled rows ----
        {
            const float* src = Kp + ((size_t)b * NKEY + kbase + skey) * DD + sd0;
            f32x4 f0 = *(const f32x4*)src;
            f32x4 f1 = *(const f32x4*)(src + 4);
            half8 h;
#pragma unroll
            for (int j = 0; j < 4; ++j) {
                h[j]     = (_Float16)f0[j];
                h[4 + j] = (_Float16)f1[j];
            }
            const int off = (skey * 128 + sd0 * 2) ^ ((skey & 7) << 4);
            *(half8*)(Ksm + off) = h;
        }
        // ---- stage V tile transposed ----
        {
            const float* src = Vp + ((size_t)b * NKEY + kbase + vkey) * DD + vd0;
            f32x4 f0 = *(const f32x4*)src;
            f32x4 f1 = *(const f32x4*)(src + 4);
#pragma unroll
            for (int j = 0; j < 8; ++j) {
                const float x = (j < 4) ? f0[j] : f1[j - 4];
                *(_Float16*)(Vsm + (vd0 + j) * (KB * 2) + vkey * 2) = (_Float16)x;
            }
        }
        __syncthreads();

        // ---- QK^T ----
        f32x4 s0 = zf, s1 = zf;
#pragma unroll
        for (int c = 0; c < 2; ++c) {
            const int key0 = lr;
            const half8 kb0 = *(const half8*)(Ksm +
                ((key0 * 128 + c * 64 + g * 16) ^ ((key0 & 7) << 4)));
            s0 = __builtin_amdgcn_mfma_f32_16x16x32_f16(qf[c], kb0, s0, 0, 0, 0);
            const int key1 = 16 + lr;
            const half8 kb1 = *(const half8*)(Ksm +
                ((key1 * 128 + c * 64 + g * 16) ^ ((key1 & 7) << 4)));
            s1 = __builtin_amdgcn_mfma_f32_16x16x32_f16(qf[c], kb1, s1, 0, 0, 0);
        }

        // ---- masked online softmax ----
        const bool msk0 = (kbase + lr) >= vlen;
        const bool msk1 = (kbase + 16 + lr) >= vlen;
        float alpha[4];
        f32x4 p0, p1;
#pragma unroll
        for (int r = 0; r < 4; ++r) {
            const float v0 = msk0 ? -1e30f : s0[r];
            const float v1 = msk1 ? -1e30f : s1[r];
            float mr = fmaxf(v0, v1);
            mr = fmaxf(mr, __shfl_xor(mr, 1));
            mr = fmaxf(mr, __shfl_xor(mr, 2));
            mr = fmaxf(mr, __shfl_xor(mr, 4));
            mr = fmaxf(mr, __shfl_xor(mr, 8));
            const float mn = fmaxf(mrun[r], mr);
            alpha[r] = __expf(mrun[r] - mn);
            mrun[r] = mn;
            const float e0 = __expf(v0 - mn);
            const float e1 = __expf(v1 - mn);
            p0[r] = e0; p1[r] = e1;
            float ps = e0 + e1;
            ps += __shfl_xor(ps, 1);
            ps += __shfl_xor(ps, 2);
            ps += __shfl_xor(ps, 4);
            ps += __shfl_xor(ps, 8);
            lrun[r] = lrun[r] * alpha[r] + ps;
        }

        // ---- write P to per-wave LDS, swizzled ----
        char* pw = Psm + wv * (16 * KB * 2);
#pragma unroll
        for (int r = 0; r < 4; ++r) {
            const int q = g * 4 + r;
            const int xm = (g & 3) << 4;
            *(_Float16*)(pw + q * 64 + ((lr * 2) ^ xm))        = (_Float16)p0[r];
            *(_Float16*)(pw + q * 64 + (((16 + lr) * 2) ^ xm)) = (_Float16)p1[r];
        }

        // ---- rescale O ----
#pragma unroll
        for (int t = 0; t < 4; ++t) {
#pragma unroll
            for (int r = 0; r < 4; ++r) o[t][r] *= alpha[r];
        }

        // ---- PV ----
        const half8 pa = *(const half8*)(pw + lr * 64 +
                           ((g * 16) ^ (((lr >> 2) & 3) << 4)));
#pragma unroll
        for (int t = 0; t < 4; ++t) {
            const half8 vb = *(const half8*)(Vsm + (t * 16 + lr) * 64 + g * 16);
            o[t] = __builtin_amdgcn_mfma_f32_16x16x32_f16(pa, vb, o[t], 0, 0, 0);
        }
    }

    // ---- epilogue ----
    if (nseg == 1) {
#pragma unroll
        for (int r = 0; r < 4; ++r) {
            const float inv = 1.0f / lrun[r];
            const int qrow = qt * 64 + wv * 16 + g * 4 + r;
            float* dst = Op + ((size_t)b * NQ + qrow) * DD;
#pragma unroll
            for (int t = 0; t < 4; ++t)
                dst[t * 16 + lr] = o[t][r] * inv;
        }
    } else {
#pragma unroll
        for (int r = 0; r < 4; ++r) {
            const int qrow = qt * 64 + wv * 16 + g * 4 + r;
            float* dst = Opart + ((size_t)(b * nseg + s) * NQ + qrow) * DD;
#pragma unroll
            for (int t = 0; t < 4; ++t)
                dst[t * 16 + lr] = o[t][r];
            if (lr == 0)
                ml[(size_t)(b * nseg + s) * NQ + qrow] = make_float2(mrun[r], lrun[r]);
        }
    }
}

// ---------------- kernel 2: merge segment partials ----------------
__global__ __launch_bounds__(256) void attn_merge(
    const float* __restrict__ Opart, const float2* __restrict__ ml,
    float* __restrict__ Op, int nseg)
{
    const int lane = threadIdx.x & 63;
    const int row  = blockIdx.x * 4 + (threadIdx.x >> 6);
    const int b = row >> 11;          // row / NQ
    const int q = row & (NQ - 1);

    float2 myml = make_float2(-1e30f, 0.f);
    if (lane < nseg)
        myml = ml[(size_t)(b * nseg + lane) * NQ + q];

    float M = -1e30f;
    for (int ss = 0; ss < nseg; ++ss)
        M = fmaxf(M, __shfl(myml.x, ss));

    float L = 0.f, acc = 0.f;
    for (int ss = 0; ss < nseg; ++ss) {
        const float ms = __shfl(myml.x, ss);
        const float ls = __shfl(myml.y, ss);
        if (ls > 0.f) {
            const float w = __expf(ms - M);
            L += w * ls;
            acc += w * Opart[((size_t)(b * nseg + ss) * NQ + q) * DD + lane];
        }
    }
    Op[((size_t)b * NQ + q) * DD + lane] = acc / L;
}

extern "C" void kernel_launch(void* const* d_in, const int* in_sizes, int n_in,
                              void* d_out, int out_size, void* d_ws, size_t ws_size,
                              hipStream_t stream) {
    const float* Qp = (const float*)d_in[0];
    const float* Kp = (const float*)d_in[1];
    const float* Vp = (const float*)d_in[2];
    const int*   VL = (const int*)d_in[3];
    float* Op = (float*)d_out;

    // choose segment count that fits in workspace
    int nseg = 8;
    while (nseg > 1) {
        size_t need = (size_t)NB * nseg * NQ * DD * 4   // Opart
                    + (size_t)NB * nseg * NQ * 8;       // ml (float2)
        if (ws_size >= need) break;
        nseg >>= 1;
    }

    float*  Opart = (float*)d_ws;
    float2* ml    = (float2*)((char*)d_ws + (size_t)NB * nseg * NQ * DD * 4);

    dim3 block(256);
    dim3 grid1(nseg * NB * 32);
    hipLaunchKernelGGL(attn_partial, grid1, block, 0, stream,
                       Qp, Kp, Vp, VL, Opart, ml, Op, nseg);

    if (nseg > 1) {
        dim3 grid2(NB * NQ / 4);
        hipLaunchKernelGGL(attn_merge, grid2, block, 0, stream,
                           Opart, ml, Op, nseg);
    }
}

// Round 5
// 40.895 us; speedup vs baseline: 2.0672x; 1.1805x over previous
//
#include <hip/hip_runtime.h>

typedef float    f32x4  __attribute__((ext_vector_type(4)));
typedef float    f32x16 __attribute__((ext_vector_type(16)));
typedef _Float16 half8  __attribute__((ext_vector_type(8)));

constexpr int NB = 8;
constexpr int NQ = 2048;
constexpr int NKEY = 2048;
constexpr int DD = 64;
constexpr int KB = 32;    // keys per KV tile
constexpr int QBLK = 128; // q rows per block (4 waves x 32)

__device__ inline unsigned pkh(float a, float b) {
    return __builtin_bit_cast(unsigned, __builtin_amdgcn_cvt_pkrtz(a, b));
}

// ---------------- kernel 1: per-segment flash partials ----------------
__global__ __launch_bounds__(256, 4) void attn_partial(
    const float* __restrict__ Qp, const float* __restrict__ Kp,
    const float* __restrict__ Vp, const int* __restrict__ VL,
    float* __restrict__ Opart, float2* __restrict__ ml,
    float* __restrict__ Op, int nseg)
{
    // K tile: 32 keys x 64 d halves, rows 128B, XOR-swizzled (verified R1/R2)
    __shared__ alignas(16) char Ksm[KB * DD * 2];
    // V tile transposed: 64 d rows x 32 keys halves, 80B stride (bank walk)
    __shared__ alignas(16) char Vsm[DD * 80];

    const int tid  = threadIdx.x;
    const int wv   = tid >> 6;
    const int lane = tid & 63;
    const int ql   = lane & 31;
    const int hi   = lane >> 5;

    const int s   = blockIdx.x / (NB * (NQ / QBLK));
    const int rem = blockIdx.x % (NB * (NQ / QBLK));
    const int b   = rem >> 4;
    const int qt  = rem & 15;
    const int qbase = qt * QBLK + wv * 32;

    const int vlen = VL[b];
    const int SEG  = NKEY / nseg;
    const int kstart = s * SEG;
    const int kend   = min(kstart + SEG, vlen);

    if (kstart >= vlen) {
        if (tid < QBLK)
            ml[(size_t)(b * nseg + s) * NQ + qt * QBLK + tid] = make_float2(-1e30f, 0.f);
        return;
    }

    // ---- Q B-fragments: lane holds Q[qbase+ql][d = c*16 + hi*8 + j], scale folded ----
    const float* qsrc = Qp + ((size_t)b * NQ + qbase + ql) * DD;
    half8 qf[4];
#pragma unroll
    for (int c = 0; c < 4; ++c) {
        f32x4 f0 = *(const f32x4*)(qsrc + c * 16 + hi * 8);
        f32x4 f1 = *(const f32x4*)(qsrc + c * 16 + hi * 8 + 4);
        half8 h;
#pragma unroll
        for (int j = 0; j < 4; ++j) {
            h[j]     = (_Float16)(f0[j] * 0.125f);
            h[4 + j] = (_Float16)(f1[j] * 0.125f);
        }
        qf[c] = h;
    }

    f32x16 o0 = {}, o1 = {};
    float mrun = -1e30f, lrun = 0.f;

    const int skey = tid >> 3;
    const int sd0  = (tid & 7) * 8;
    const int vkey = tid & 31;
    const int vd0  = (tid >> 5) * 8;

    const int numt = (kend - kstart + KB - 1) / KB;

    for (int it = 0; it < numt; ++it) {
        const int kbase = kstart + it * KB;
        __syncthreads();

        // ---- stage K tile (f32 -> f16), swizzled rows ----
        {
            const float* src = Kp + ((size_t)b * NKEY + kbase + skey) * DD + sd0;
            f32x4 f0 = *(const f32x4*)src;
            f32x4 f1 = *(const f32x4*)(src + 4);
            half8 h;
#pragma unroll
            for (int j = 0; j < 4; ++j) {
                h[j]     = (_Float16)f0[j];
                h[4 + j] = (_Float16)f1[j];
            }
            const int off = (skey * 128 + sd0 * 2) ^ ((skey & 7) << 4);
            *(half8*)(Ksm + off) = h;
        }
        // ---- stage V transposed, 80B row stride ----
        {
            const float* src = Vp + ((size_t)b * NKEY + kbase + vkey) * DD + vd0;
            f32x4 f0 = *(const f32x4*)src;
            f32x4 f1 = *(const f32x4*)(src + 4);
#pragma unroll
            for (int j = 0; j < 8; ++j) {
                const float x = (j < 4) ? f0[j] : f1[j - 4];
                *(_Float16*)(Vsm + (vd0 + j) * 80 + vkey * 2) = (_Float16)x;
            }
        }
        __syncthreads();

        // ---- swapped QK^T: S^T[k][q], lane owns q=ql, 16 k-rows in regs ----
        f32x16 sv = {};
#pragma unroll
        for (int c = 0; c < 4; ++c) {
            const half8 kf = *(const half8*)(Ksm +
                ((ql * 128 + c * 32 + hi * 16) ^ ((ql & 7) << 4)));
            sv = __builtin_amdgcn_mfma_f32_32x32x16_f16(kf, qf[c], sv, 0, 0, 0);
        }

        // ---- mask (boundary tile only; block-uniform branch) ----
        if (kbase + KB > vlen) {
#pragma unroll
            for (int r = 0; r < 16; ++r) {
                const int krow = (r & 3) + 8 * (r >> 2) + 4 * hi;
                sv[r] = (kbase + krow < vlen) ? sv[r] : -1e30f;
            }
        }

        // ---- in-register online softmax (per-lane state is for q = ql) ----
        float mr = sv[0];
#pragma unroll
        for (int r = 1; r < 16; ++r) mr = fmaxf(mr, sv[r]);
        mr = fmaxf(mr, __shfl_xor(mr, 32));
        const float mn = fmaxf(mrun, mr);
        const float alpha = __expf(mrun - mn);
        float ps = 0.f;
#pragma unroll
        for (int r = 0; r < 16; ++r) {
            sv[r] = __expf(sv[r] - mn);   // P in place
            ps += sv[r];
        }
        ps += __shfl_xor(ps, 32);
        lrun = lrun * alpha + ps;
        mrun = mn;

        // ---- rescale O: row r is q = (r&3)+8*(r>>2)+4*hi, need THAT q's alpha ----
        // (R3/R4 bug: used per-lane alpha(q=ql) for all 16 rows)
#pragma unroll
        for (int r = 0; r < 16; ++r) {
            const int qr = (r & 3) + 8 * (r >> 2) + 4 * hi;
            const float ar = __shfl(alpha, qr);
            o0[r] *= ar;
            o1[r] *= ar;
        }

        // ---- P (f32 regs) -> f16 A-fragments via cvt_pkrtz + shfl_xor(32) ----
        const unsigned w0 = pkh(sv[0],  sv[1]),  w1 = pkh(sv[2],  sv[3]);
        const unsigned w2 = pkh(sv[4],  sv[5]),  w3 = pkh(sv[6],  sv[7]);
        const unsigned w4 = pkh(sv[8],  sv[9]),  w5 = pkh(sv[10], sv[11]);
        const unsigned w6 = pkh(sv[12], sv[13]), w7 = pkh(sv[14], sv[15]);
        const unsigned p0 = __shfl_xor(w0, 32), p1 = __shfl_xor(w1, 32);
        const unsigned p2 = __shfl_xor(w2, 32), p3 = __shfl_xor(w3, 32);
        const unsigned p4 = __shfl_xor(w4, 32), p5 = __shfl_xor(w5, 32);
        const unsigned p6 = __shfl_xor(w6, 32), p7 = __shfl_xor(w7, 32);
        const bool h1 = (hi != 0);
        union { unsigned u[4]; half8 h; } A0, A1;
        // A0: keys hi*8 + {0..7}
        A0.u[0] = h1 ? p2 : w0;  A0.u[1] = h1 ? p3 : w1;
        A0.u[2] = h1 ? w2 : p0;  A0.u[3] = h1 ? w3 : p1;
        // A1: keys 16 + hi*8 + {0..7}
        A1.u[0] = h1 ? p6 : w4;  A1.u[1] = h1 ? p7 : w5;
        A1.u[2] = h1 ? w6 : p4;  A1.u[3] = h1 ? w7 : p5;

        // ---- PV: O[q][d] += P * V ----
#pragma unroll
        for (int t = 0; t < 2; ++t) {
            const half8 vb0 = *(const half8*)(Vsm + ql * 80        + t * 32 + hi * 16);
            const half8 vb1 = *(const half8*)(Vsm + (32 + ql) * 80 + t * 32 + hi * 16);
            const half8 pa = (t == 0) ? A0.h : A1.h;
            o0 = __builtin_amdgcn_mfma_f32_32x32x16_f16(pa, vb0, o0, 0, 0, 0);
            o1 = __builtin_amdgcn_mfma_f32_32x32x16_f16(pa, vb1, o1, 0, 0, 0);
        }
    }

    // ---- epilogue: O rows q=(r&3)+8*(r>>2)+4*hi, cols d=ql+32u ----
    if (nseg == 1) {
#pragma unroll
        for (int r = 0; r < 16; ++r) {
            const int qr = (r & 3) + 8 * (r >> 2) + 4 * hi;
            const float inv = 1.0f / __shfl(lrun, qr);
            float* dst = Op + ((size_t)b * NQ + qbase + qr) * DD + ql;
            dst[0]  = o0[r] * inv;
            dst[32] = o1[r] * inv;
        }
    } else {
        float* dst0 = Opart + ((size_t)(b * nseg + s) * NQ + qbase) * DD;
#pragma unroll
        for (int r = 0; r < 16; ++r) {
            const int qr = (r & 3) + 8 * (r >> 2) + 4 * hi;
            float* dst = dst0 + (size_t)qr * DD + ql;
            dst[0]  = o0[r];
            dst[32] = o1[r];
        }
        if (hi == 0)
            ml[(size_t)(b * nseg + s) * NQ + qbase + ql] = make_float2(mrun, lrun);
    }
}

// ---------------- kernel 2: merge segment partials ----------------
__global__ __launch_bounds__(256) void attn_merge(
    const float* __restrict__ Opart, const float2* __restrict__ ml,
    float* __restrict__ Op, int nseg)
{
    const int lane = threadIdx.x & 63;
    const int row  = blockIdx.x * 4 + (threadIdx.x >> 6);
    const int b = row >> 11;
    const int q = row & (NQ - 1);

    float2 myml = make_float2(-1e30f, 0.f);
    if (lane < nseg)
        myml = ml[(size_t)(b * nseg + lane) * NQ + q];

    float M = -1e30f;
    for (int ss = 0; ss < nseg; ++ss)
        M = fmaxf(M, __shfl(myml.x, ss));

    float L = 0.f, acc = 0.f;
    for (int ss = 0; ss < nseg; ++ss) {
        const float ms = __shfl(myml.x, ss);
        const float ls = __shfl(myml.y, ss);
        if (ls > 0.f) {
            const float w = __expf(ms - M);
            L += w * ls;
            acc += w * Opart[((size_t)(b * nseg + ss) * NQ + q) * DD + lane];
        }
    }
    Op[((size_t)b * NQ + q) * DD + lane] = acc / L;
}

extern "C" void kernel_launch(void* const* d_in, const int* in_sizes, int n_in,
                              void* d_out, int out_size, void* d_ws, size_t ws_size,
                              hipStream_t stream) {
    const float* Qp = (const float*)d_in[0];
    const float* Kp = (const float*)d_in[1];
    const float* Vp = (const float*)d_in[2];
    const int*   VL = (const int*)d_in[3];
    float* Op = (float*)d_out;

    int nseg = 8;
    while (nseg > 1) {
        size_t need = (size_t)NB * nseg * NQ * DD * 4
                    + (size_t)NB * nseg * NQ * 8;
        if (ws_size >= need) break;
        nseg >>= 1;
    }

    float*  Opart = (float*)d_ws;
    float2* ml    = (float2*)((char*)d_ws + (size_t)NB * nseg * NQ * DD * 4);

    dim3 block(256);
    dim3 grid1(nseg * NB * (NQ / QBLK));
    hipLaunchKernelGGL(attn_partial, grid1, block, 0, stream,
                       Qp, Kp, Vp, VL, Opart, ml, Op, nseg);

    if (nseg > 1) {
        dim3 grid2(NB * NQ / 4);
        hipLaunchKernelGGL(attn_merge, grid2, block, 0, stream,
                           Opart, ml, Op, nseg);
    }
}

// Round 6
// 39.829 us; speedup vs baseline: 2.1226x; 1.0268x over previous
//
#include <hip/hip_runtime.h>

typedef float    f32x4  __attribute__((ext_vector_type(4)));
typedef float    f32x16 __attribute__((ext_vector_type(16)));
typedef _Float16 half8  __attribute__((ext_vector_type(8)));

constexpr int NB = 8;
constexpr int NQ = 2048;
constexpr int NKEY = 2048;
constexpr int DD = 64;
constexpr int KB = 64;    // keys per iteration (two 32-key chunks)
constexpr int QBLK = 128; // q rows per block (4 waves x 32)

// scores kept in log2 domain: fold log2(e) into the 1/sqrt(d) scale
#define QSCALE (0.125f * 1.44269504088896340736f)

__device__ inline unsigned pkh(float a, float b) {
    return __builtin_bit_cast(unsigned, __builtin_amdgcn_cvt_pkrtz(a, b));
}

// Exchange P (f32 C-layout regs) -> f16 A-fragments and do PV from global V.
// Layout verified in R5: A0 = keys hi*8+{0..7}, A1 = keys 16+hi*8+{0..7};
// vb for (t,dblk): V[kb + t*16 + hi*8 + j][dblk*32 + ql].
__device__ __forceinline__ void pv_chunk(
    const f32x16& sv, const float* __restrict__ vbase /* row kb, col 0 */,
    int hi, int ql, f32x16& o0, f32x16& o1)
{
    const unsigned w0 = pkh(sv[0],  sv[1]),  w1 = pkh(sv[2],  sv[3]);
    const unsigned w2 = pkh(sv[4],  sv[5]),  w3 = pkh(sv[6],  sv[7]);
    const unsigned w4 = pkh(sv[8],  sv[9]),  w5 = pkh(sv[10], sv[11]);
    const unsigned w6 = pkh(sv[12], sv[13]), w7 = pkh(sv[14], sv[15]);
    const unsigned p0 = __shfl_xor(w0, 32), p1 = __shfl_xor(w1, 32);
    const unsigned p2 = __shfl_xor(w2, 32), p3 = __shfl_xor(w3, 32);
    const unsigned p4 = __shfl_xor(w4, 32), p5 = __shfl_xor(w5, 32);
    const unsigned p6 = __shfl_xor(w6, 32), p7 = __shfl_xor(w7, 32);
    const bool h1 = (hi != 0);
    union { unsigned u[4]; half8 h; } A0, A1;
    A0.u[0] = h1 ? p2 : w0;  A0.u[1] = h1 ? p3 : w1;
    A0.u[2] = h1 ? w2 : p0;  A0.u[3] = h1 ? w3 : p1;
    A1.u[0] = h1 ? p6 : w4;  A1.u[1] = h1 ? p7 : w5;
    A1.u[2] = h1 ? w6 : p4;  A1.u[3] = h1 ? w7 : p5;

#pragma unroll
    for (int t = 0; t < 2; ++t) {
        const float* vr = vbase + (size_t)(t * 16 + hi * 8) * DD + ql;
        half8 vb0, vb1;
#pragma unroll
        for (int j = 0; j < 8; ++j) {
            vb0[j] = (_Float16)vr[(size_t)j * DD];
            vb1[j] = (_Float16)vr[(size_t)j * DD + 32];
        }
        const half8 pa = (t == 0) ? A0.h : A1.h;
        o0 = __builtin_amdgcn_mfma_f32_32x32x16_f16(pa, vb0, o0, 0, 0, 0);
        o1 = __builtin_amdgcn_mfma_f32_32x32x16_f16(pa, vb1, o1, 0, 0, 0);
    }
}

// ---------------- kernel 1: per-segment flash partials ----------------
__global__ __launch_bounds__(256) void attn_partial(
    const float* __restrict__ Qp, const float* __restrict__ Kp,
    const float* __restrict__ Vp, const int* __restrict__ VL,
    float* __restrict__ Opart, float2* __restrict__ ml,
    float* __restrict__ Op, int nseg)
{
    // K tile: 64 keys x 64 d halves, rows 128B, XOR-swizzled (verified)
    __shared__ alignas(16) char Ksm[KB * DD * 2];

    const int tid  = threadIdx.x;
    const int wv   = tid >> 6;
    const int lane = tid & 63;
    const int ql   = lane & 31;
    const int hi   = lane >> 5;

    const int s   = blockIdx.x / (NB * (NQ / QBLK));
    const int rem = blockIdx.x % (NB * (NQ / QBLK));
    const int b   = rem >> 4;
    const int qt  = rem & 15;
    const int qbase = qt * QBLK + wv * 32;

    const int vlen = VL[b];
    const int SEG  = NKEY / nseg;
    const int kstart = s * SEG;
    const int kend   = min(kstart + SEG, vlen);

    if (kstart >= vlen) {
        if (tid < QBLK)
            ml[(size_t)(b * nseg + s) * NQ + qt * QBLK + tid] = make_float2(-1e30f, 0.f);
        return;
    }

    // ---- Q B-fragments: lane holds Q[qbase+ql][d = c*16 + hi*8 + j] ----
    const float* qsrc = Qp + ((size_t)b * NQ + qbase + ql) * DD;
    half8 qf[4];
#pragma unroll
    for (int c = 0; c < 4; ++c) {
        f32x4 f0 = *(const f32x4*)(qsrc + c * 16 + hi * 8);
        f32x4 f1 = *(const f32x4*)(qsrc + c * 16 + hi * 8 + 4);
        half8 h;
#pragma unroll
        for (int j = 0; j < 4; ++j) {
            h[j]     = (_Float16)(f0[j] * QSCALE);
            h[4 + j] = (_Float16)(f1[j] * QSCALE);
        }
        qf[c] = h;
    }

    f32x16 o0 = {}, o1 = {};
    float mrun = -1e30f, lrun = 0.f;

    const int skey = tid >> 3;          // 0..31
    const int sd0  = (tid & 7) * 8;     // 0..56

    const int numt = (kend - kstart + KB - 1) / KB;

    for (int it = 0; it < numt; ++it) {
        const int kbase = kstart + it * KB;
        __syncthreads();

        // ---- stage K tile (64 rows, f32 -> f16), swizzled ----
#pragma unroll
        for (int u = 0; u < 2; ++u) {
            const int row = skey + u * 32;
            const float* src = Kp + ((size_t)b * NKEY + kbase + row) * DD + sd0;
            f32x4 f0 = *(const f32x4*)src;
            f32x4 f1 = *(const f32x4*)(src + 4);
            half8 h;
#pragma unroll
            for (int j = 0; j < 4; ++j) {
                h[j]     = (_Float16)f0[j];
                h[4 + j] = (_Float16)f1[j];
            }
            const int off = (row * 128 + sd0 * 2) ^ ((row & 7) << 4);
            *(half8*)(Ksm + off) = h;
        }
        __syncthreads();

        // ---- swapped QK^T, two independent 32-key chunks ----
        f32x16 svA = {}, svB = {};
#pragma unroll
        for (int c = 0; c < 4; ++c) {
            const half8 kfA = *(const half8*)(Ksm +
                ((ql * 128 + c * 32 + hi * 16) ^ ((ql & 7) << 4)));
            svA = __builtin_amdgcn_mfma_f32_32x32x16_f16(kfA, qf[c], svA, 0, 0, 0);
            const half8 kfB = *(const half8*)(Ksm +
                (((32 + ql) * 128 + c * 32 + hi * 16) ^ ((ql & 7) << 4)));
            svB = __builtin_amdgcn_mfma_f32_32x32x16_f16(kfB, qf[c], svB, 0, 0, 0);
        }

        // ---- mask (boundary iteration only; block-uniform branch) ----
        if (kbase + KB > vlen) {
#pragma unroll
            for (int r = 0; r < 16; ++r) {
                const int krow = (r & 3) + 8 * (r >> 2) + 4 * hi;
                svA[r] = (kbase + krow < vlen)      ? svA[r] : -1e30f;
                svB[r] = (kbase + 32 + krow < vlen) ? svB[r] : -1e30f;
            }
        }

        // ---- online softmax in log2 domain (per-lane state is q = ql) ----
        float mx[16];
#pragma unroll
        for (int r = 0; r < 16; ++r) mx[r] = fmaxf(svA[r], svB[r]);
#pragma unroll
        for (int st = 8; st > 0; st >>= 1)
#pragma unroll
            for (int r = 0; r < st; ++r) mx[r] = fmaxf(mx[r], mx[r + st]);
        float mr = fmaxf(mx[0], __shfl_xor(mx[0], 32));

        // defer-max: skip rescale if max grew <= 8 (P bounded by 2^8)
        if (!__all(mr <= mrun + 8.f)) {
            const float mn = fmaxf(mrun, mr);
            const float alpha = __builtin_amdgcn_exp2f(mrun - mn);
            lrun *= alpha;
            mrun = mn;
#pragma unroll
            for (int r = 0; r < 16; ++r) {
                const int qr = (r & 3) + 8 * (r >> 2) + 4 * hi;
                const float ar = __shfl(alpha, qr);
                o0[r] *= ar;
                o1[r] *= ar;
            }
        }

#pragma unroll
        for (int r = 0; r < 16; ++r) {
            svA[r] = __builtin_amdgcn_exp2f(svA[r] - mrun);
            svB[r] = __builtin_amdgcn_exp2f(svB[r] - mrun);
        }
        float sx[16];
#pragma unroll
        for (int r = 0; r < 16; ++r) sx[r] = svA[r] + svB[r];
#pragma unroll
        for (int st = 8; st > 0; st >>= 1)
#pragma unroll
            for (int r = 0; r < st; ++r) sx[r] += sx[r + st];
        lrun += sx[0] + __shfl_xor(sx[0], 32);

        // ---- PV for both chunks (V direct from global, L2-resident) ----
        const float* vbaseA = Vp + ((size_t)b * NKEY + kbase) * DD;
        pv_chunk(svA, vbaseA, hi, ql, o0, o1);
        pv_chunk(svB, vbaseA + (size_t)32 * DD, hi, ql, o0, o1);
    }

    // ---- epilogue: O rows q=(r&3)+8*(r>>2)+4*hi, cols d=ql+32u ----
    if (nseg == 1) {
#pragma unroll
        for (int r = 0; r < 16; ++r) {
            const int qr = (r & 3) + 8 * (r >> 2) + 4 * hi;
            const float inv = 1.0f / __shfl(lrun, qr);
            float* dst = Op + ((size_t)b * NQ + qbase + qr) * DD + ql;
            dst[0]  = o0[r] * inv;
            dst[32] = o1[r] * inv;
        }
    } else {
        float* dst0 = Opart + ((size_t)(b * nseg + s) * NQ + qbase) * DD;
#pragma unroll
        for (int r = 0; r < 16; ++r) {
            const int qr = (r & 3) + 8 * (r >> 2) + 4 * hi;
            float* dst = dst0 + (size_t)qr * DD + ql;
            dst[0]  = o0[r];
            dst[32] = o1[r];
        }
        if (hi == 0)
            ml[(size_t)(b * nseg + s) * NQ + qbase + ql] = make_float2(mrun, lrun);
    }
}

// ---------------- kernel 2: merge segment partials (log2-domain m) ----------------
__global__ __launch_bounds__(256) void attn_merge(
    const float* __restrict__ Opart, const float2* __restrict__ ml,
    float* __restrict__ Op, int nseg)
{
    const int lane = threadIdx.x & 63;
    const int row  = blockIdx.x * 4 + (threadIdx.x >> 6);
    const int b = row >> 11;
    const int q = row & (NQ - 1);

    float2 myml = make_float2(-1e30f, 0.f);
    if (lane < nseg)
        myml = ml[(size_t)(b * nseg + lane) * NQ + q];

    float M = -1e30f;
    for (int ss = 0; ss < nseg; ++ss)
        M = fmaxf(M, __shfl(myml.x, ss));

    float L = 0.f, acc = 0.f;
    for (int ss = 0; ss < nseg; ++ss) {
        const float ms = __shfl(myml.x, ss);
        const float ls = __shfl(myml.y, ss);
        if (ls > 0.f) {
            const float w = __builtin_amdgcn_exp2f(ms - M);
            L += w * ls;
            acc += w * Opart[((size_t)(b * nseg + ss) * NQ + q) * DD + lane];
        }
    }
    Op[((size_t)b * NQ + q) * DD + lane] = acc / L;
}

extern "C" void kernel_launch(void* const* d_in, const int* in_sizes, int n_in,
                              void* d_out, int out_size, void* d_ws, size_t ws_size,
                              hipStream_t stream) {
    const float* Qp = (const float*)d_in[0];
    const float* Kp = (const float*)d_in[1];
    const float* Vp = (const float*)d_in[2];
    const int*   VL = (const int*)d_in[3];
    float* Op = (float*)d_out;

    int nseg = 8;
    while (nseg > 1) {
        size_t need = (size_t)NB * nseg * NQ * DD * 4
                    + (size_t)NB * nseg * NQ * 8;
        if (ws_size >= need) break;
        nseg >>= 1;
    }

    float*  Opart = (float*)d_ws;
    float2* ml    = (float2*)((char*)d_ws + (size_t)NB * nseg * NQ * DD * 4);

    dim3 block(256);
    dim3 grid1(nseg * NB * (NQ / QBLK));
    hipLaunchKernelGGL(attn_partial, grid1, block, 0, stream,
                       Qp, Kp, Vp, VL, Opart, ml, Op, nseg);

    if (nseg > 1) {
        dim3 grid2(NB * NQ / 4);
        hipLaunchKernelGGL(attn_merge, grid2, block, 0, stream,
                           Opart, ml, Op, nseg);
    }
}